// Round 6
// baseline (349.655 us; speedup 1.0000x reference)
//
#include <hip/hip_runtime.h>
#include <hip/hip_bf16.h>

#define N_NODES 50000
#define N_EDGES 800000
#define IN_DIM 128
#define HIDDEN 128
#define OUT_DIM 40

#define SCAN_BS 1024
#define SCAN_BLOCKS ((N_NODES + SCAN_BS - 1) / SCAN_BS)   // 49

#define N_BUCKETS 8
#define BUCKET_NODES (N_NODES / N_BUCKETS)                // 6250
#define HIST_STRIDE 50176                                 // line-aligned copy stride
#define EDGE_BLOCKS (N_EDGES / 256)                       // 3125 exact

struct __align__(8) Edge { int s; float w; };

// ---- 1) XCD-private histograms: copy = blockIdx&7 (heuristic XCD id).
// Each 200KB copy is touched by one XCD only -> L2-local atomics, no bounce.
__global__ __launch_bounds__(256) void hist8_kernel(const int* __restrict__ dst,
                                                    int* __restrict__ hist8)
{
    int i = blockIdx.x * 256 + threadIdx.x;
    int copy = blockIdx.x & (N_BUCKETS - 1);
    atomicAdd(&hist8[copy * HIST_STRIDE + dst[i]], 1);
}

// ---- 2a) reduce 8 copies -> cnt, plus per-block partial sums --------------
__global__ __launch_bounds__(SCAN_BS) void scan_partial(const int* __restrict__ hist8,
                                                        int* __restrict__ cnt,
                                                        int* __restrict__ block_sums)
{
    __shared__ int red[SCAN_BS / 64];
    int i = blockIdx.x * SCAN_BS + threadIdx.x;
    int v = 0;
    if (i < N_NODES) {
        #pragma unroll
        for (int c = 0; c < N_BUCKETS; ++c) v += hist8[c * HIST_STRIDE + i];
        cnt[i] = v;
    }
    int s = v;
    for (int off = 32; off > 0; off >>= 1) s += __shfl_down(s, off, 64);
    int wave = threadIdx.x >> 6, lane = threadIdx.x & 63;
    if (lane == 0) red[wave] = s;
    __syncthreads();
    if (threadIdx.x == 0) {
        int t = 0;
        #pragma unroll
        for (int wv = 0; wv < SCAN_BS / 64; ++wv) t += red[wv];
        block_sums[blockIdx.x] = t;
    }
}

// ---- 2b) scan the 49 block sums (one wave) --------------------------------
__global__ __launch_bounds__(64) void scan_sums(int* __restrict__ block_sums,
                                                int* __restrict__ row_ptr,
                                                int* __restrict__ gbase)
{
    int t = threadIdx.x;
    int v = (t < SCAN_BLOCKS) ? block_sums[t] : 0;
    int incl = v;
    for (int off = 1; off < 64; off <<= 1) {
        int u = __shfl_up(incl, off, 64);
        if (t >= off) incl += u;
    }
    if (t < SCAN_BLOCKS) block_sums[t] = incl - v;
    if (t == 0) { row_ptr[N_NODES] = N_EDGES; gbase[N_BUCKETS] = N_EDGES; }
}

// ---- 2c) block-local exclusive scan + offset; also bucket bases -----------
__global__ __launch_bounds__(SCAN_BS) void scan_final(const int* __restrict__ cnt,
                                                      const int* __restrict__ block_sums,
                                                      int* __restrict__ row_ptr,
                                                      int* __restrict__ cursor,
                                                      int* __restrict__ gbase,
                                                      int* __restrict__ gcursorA)
{
    __shared__ int tmp[SCAN_BS];
    int t = threadIdx.x;
    int i = blockIdx.x * SCAN_BS + t;
    int v = (i < N_NODES) ? cnt[i] : 0;
    tmp[t] = v;
    __syncthreads();
    for (int off = 1; off < SCAN_BS; off <<= 1) {
        int u = (t >= off) ? tmp[t - off] : 0;
        __syncthreads();
        tmp[t] += u;
        __syncthreads();
    }
    if (i < N_NODES) {
        int excl = tmp[t] - v + block_sums[blockIdx.x];
        row_ptr[i] = excl;
        cursor[i]  = excl;
        if (i % BUCKET_NODES == 0) {          // bucket boundary
            int q = i / BUCKET_NODES;
            gbase[q]    = excl;
            gcursorA[q] = excl;
        }
    }
}

// ---- 3a) Phase A: bin edges by dst-bucket into staged chunks --------------
// LDS counters reserve a contiguous window per bin per block -> writes are
// chunked (avg 32 x 16B = 512B per bin), no cross-XCD false sharing.
__global__ __launch_bounds__(256) void scatterA(const int* __restrict__ src,
                                                const int* __restrict__ dst,
                                                const float* __restrict__ w,
                                                int* __restrict__ gcursorA,
                                                int4* __restrict__ staged)
{
    __shared__ int bin_cnt[N_BUCKETS];
    __shared__ int bin_base[N_BUCKETS];
    __shared__ int bin_fill[N_BUCKETS];
    int t = threadIdx.x;
    int i = blockIdx.x * 256 + t;
    if (t < N_BUCKETS) { bin_cnt[t] = 0; bin_fill[t] = 0; }
    __syncthreads();
    int d = dst[i];
    int s = src[i];
    float wv = w[i];
    unsigned q = (unsigned)d / BUCKET_NODES;
    atomicAdd(&bin_cnt[q], 1);
    __syncthreads();
    if (t < N_BUCKETS) bin_base[t] = atomicAdd(&gcursorA[t], bin_cnt[t]);
    __syncthreads();
    int off = atomicAdd(&bin_fill[q], 1);
    int pos = bin_base[q] + off;
    staged[pos] = make_int4(s, __float_as_int(wv), d, 0);
}

// ---- 3b) Phase B: per-bucket exact scatter (one XCD owns each bucket) -----
__global__ __launch_bounds__(256) void scatterB(const int4* __restrict__ staged,
                                                const int* __restrict__ gbase,
                                                int* __restrict__ cursor,
                                                Edge* __restrict__ edges)
{
    int q   = blockIdx.x & (N_BUCKETS - 1);
    int idx = blockIdx.x >> 3;                 // 0..255 within bucket
    int beg = gbase[q];
    int end = gbase[q + 1];
    for (int i = beg + idx * 256 + threadIdx.x; i < end; i += 256 * 256) {
        int4 st = staged[i];
        int pos = atomicAdd(&cursor[st.z], 1);
        Edge ed; ed.s = st.x; ed.w = __int_as_float(st.y);
        edges[pos] = ed;
    }
}

// ---- gemm1: y = x @ W1 (fp32 in, bf16 out), 16 rows/block -----------------
#define G1_ROWS 16
__global__ __launch_bounds__(128) void gemm1_kernel(const float* __restrict__ x,
                                                    const float* __restrict__ W1,
                                                    __hip_bfloat16* __restrict__ y)
{
    __shared__ float xs[G1_ROWS][IN_DIM];
    int row0 = blockIdx.x * G1_ROWS;
    int col = threadIdx.x;
    #pragma unroll
    for (int r = 0; r < G1_ROWS; ++r)
        xs[r][col] = x[(long long)(row0 + r) * IN_DIM + col];
    __syncthreads();
    float acc[G1_ROWS];
    #pragma unroll
    for (int r = 0; r < G1_ROWS; ++r) acc[r] = 0.f;
    #pragma unroll 4
    for (int k = 0; k < IN_DIM; ++k) {
        float wv = W1[k * HIDDEN + col];
        #pragma unroll
        for (int r = 0; r < G1_ROWS; ++r)
            acc[r] = fmaf(xs[r][k], wv, acc[r]);
    }
    #pragma unroll
    for (int r = 0; r < G1_ROWS; ++r)
        y[(long long)(row0 + r) * HIDDEN + col] = __float2bfloat16(acc[r]);
}

// ---- spmm1g: g = relu(A @ y + b1) @ W2, fused epilogue --------------------
// Wave per node computes the 128-wide aggregated+relu'd row, parks it in
// LDS, then 40 lanes dot it with W2. h1 never hits global memory.
__global__ __launch_bounds__(256) void spmm1g_kernel(const int* __restrict__ row_ptr,
                                                     const Edge* __restrict__ edges,
                                                     const __hip_bfloat16* __restrict__ y,
                                                     const float* __restrict__ b1,
                                                     const float* __restrict__ W2,
                                                     __hip_bfloat16* __restrict__ g)
{
    __shared__ float ls[4][IN_DIM];            // 4 nodes/block
    int wv = threadIdx.x >> 6;
    int lane = threadIdx.x & 63;
    int node = blockIdx.x * 4 + wv;            // grid exact: 12500*4 = 50000
    int beg = row_ptr[node];
    int end = row_ptr[node + 1];
    const __hip_bfloat162* yv = (const __hip_bfloat162*)y;
    float ax = 0.f, ay = 0.f;
    int j = beg;
    for (; j + 3 < end; j += 4) {
        Edge e0 = edges[j];
        Edge e1 = edges[j + 1];
        Edge e2 = edges[j + 2];
        Edge e3 = edges[j + 3];
        __hip_bfloat162 v0 = yv[(long long)e0.s * 64 + lane];
        __hip_bfloat162 v1 = yv[(long long)e1.s * 64 + lane];
        __hip_bfloat162 v2 = yv[(long long)e2.s * 64 + lane];
        __hip_bfloat162 v3 = yv[(long long)e3.s * 64 + lane];
        ax = fmaf(e0.w, __low2float(v0), ax);  ay = fmaf(e0.w, __high2float(v0), ay);
        ax = fmaf(e1.w, __low2float(v1), ax);  ay = fmaf(e1.w, __high2float(v1), ay);
        ax = fmaf(e2.w, __low2float(v2), ax);  ay = fmaf(e2.w, __high2float(v2), ay);
        ax = fmaf(e3.w, __low2float(v3), ax);  ay = fmaf(e3.w, __high2float(v3), ay);
    }
    for (; j < end; ++j) {
        Edge e0 = edges[j];
        __hip_bfloat162 v0 = yv[(long long)e0.s * 64 + lane];
        ax = fmaf(e0.w, __low2float(v0), ax);
        ay = fmaf(e0.w, __high2float(v0), ay);
    }
    float2 bv = ((const float2*)b1)[lane];
    ((float2*)ls[wv])[lane] = make_float2(fmaxf(ax + bv.x, 0.f),
                                          fmaxf(ay + bv.y, 0.f));
    __syncthreads();
    if (lane < OUT_DIM) {
        const float4* hrow = (const float4*)ls[wv];
        float acc = 0.f;
        #pragma unroll 4
        for (int k4 = 0; k4 < IN_DIM / 4; ++k4) {
            float4 h4 = hrow[k4];
            acc = fmaf(h4.x, W2[(4 * k4 + 0) * OUT_DIM + lane], acc);
            acc = fmaf(h4.y, W2[(4 * k4 + 1) * OUT_DIM + lane], acc);
            acc = fmaf(h4.z, W2[(4 * k4 + 2) * OUT_DIM + lane], acc);
            acc = fmaf(h4.w, W2[(4 * k4 + 3) * OUT_DIM + lane], acc);
        }
        g[(long long)node * OUT_DIM + lane] = __float2bfloat16(acc);
    }
}

// ---- spmm2: out = A @ g + b2; wave/node, 40 active lanes ------------------
__global__ __launch_bounds__(256) void spmm2_kernel(const int* __restrict__ row_ptr,
                                                    const Edge* __restrict__ edges,
                                                    const __hip_bfloat16* __restrict__ g,
                                                    const float* __restrict__ b2,
                                                    float* __restrict__ out)
{
    int node = blockIdx.x * 4 + (threadIdx.x >> 6);
    int lane = threadIdx.x & 63;
    if (lane >= OUT_DIM) return;
    int beg = row_ptr[node];
    int end = row_ptr[node + 1];
    float acc = 0.f;
    int j = beg;
    for (; j + 3 < end; j += 4) {
        Edge e0 = edges[j];
        Edge e1 = edges[j + 1];
        Edge e2 = edges[j + 2];
        Edge e3 = edges[j + 3];
        float v0 = __bfloat162float(g[(long long)e0.s * OUT_DIM + lane]);
        float v1 = __bfloat162float(g[(long long)e1.s * OUT_DIM + lane]);
        float v2 = __bfloat162float(g[(long long)e2.s * OUT_DIM + lane]);
        float v3 = __bfloat162float(g[(long long)e3.s * OUT_DIM + lane]);
        acc = fmaf(e0.w, v0, acc);
        acc = fmaf(e1.w, v1, acc);
        acc = fmaf(e2.w, v2, acc);
        acc = fmaf(e3.w, v3, acc);
    }
    for (; j < end; ++j) {
        Edge e0 = edges[j];
        acc = fmaf(e0.w, __bfloat162float(g[(long long)e0.s * OUT_DIM + lane]), acc);
    }
    out[(long long)node * OUT_DIM + lane] = acc + b2[lane];
}

extern "C" void kernel_launch(void* const* d_in, const int* in_sizes, int n_in,
                              void* d_out, int out_size, void* d_ws, size_t ws_size,
                              hipStream_t stream)
{
    const float* x    = (const float*)d_in[0];
    const int*   esrc = (const int*)  d_in[1];
    const int*   edst = (const int*)  d_in[2];
    const float* ew   = (const float*)d_in[3];
    const float* W1   = (const float*)d_in[4];
    const float* b1   = (const float*)d_in[5];
    const float* W2   = (const float*)d_in[6];
    const float* b2   = (const float*)d_in[7];
    float* out = (float*)d_out;

    // workspace layout (~38.5 MB)
    __hip_bfloat16* y = (__hip_bfloat16*)d_ws;                   // 12.8 MB
    __hip_bfloat16* g = y + (size_t)N_NODES * HIDDEN;            // 4.0 MB
    int4* staged   = (int4*)(g + (size_t)N_NODES * OUT_DIM);     // 12.8 MB
    Edge* edges    = (Edge*)(staged + N_EDGES);                  // 6.4 MB
    int* hist8     = (int*)(edges + N_EDGES);                    // 1.6 MB
    int* cnt       = hist8 + N_BUCKETS * HIST_STRIDE;            // 200 KB
    int* row_ptr   = cnt + 50176;                                // 50001 (pad)
    int* cursor    = row_ptr + 50176;
    int* block_sums= cursor + 50176;                             // 64
    int* gbase     = block_sums + 64;                            // 9
    int* gcursorA  = gbase + 16;                                 // 8

    // build CSR (reused by both SpMMs)
    hipMemsetAsync(hist8, 0, N_BUCKETS * HIST_STRIDE * sizeof(int), stream);
    hist8_kernel<<<EDGE_BLOCKS, 256, 0, stream>>>(edst, hist8);
    scan_partial<<<SCAN_BLOCKS, SCAN_BS, 0, stream>>>(hist8, cnt, block_sums);
    scan_sums<<<1, 64, 0, stream>>>(block_sums, row_ptr, gbase);
    scan_final<<<SCAN_BLOCKS, SCAN_BS, 0, stream>>>(cnt, block_sums, row_ptr,
                                                    cursor, gbase, gcursorA);
    scatterA<<<EDGE_BLOCKS, 256, 0, stream>>>(esrc, edst, ew, gcursorA, staged);
    scatterB<<<256 * N_BUCKETS, 256, 0, stream>>>(staged, gbase, cursor, edges);

    // y = x @ W1
    gemm1_kernel<<<N_NODES / G1_ROWS, 128, 0, stream>>>(x, W1, y);
    // g = relu(A @ y + b1) @ W2   (fused)
    spmm1g_kernel<<<N_NODES / 4, 256, 0, stream>>>(row_ptr, edges, y, b1, W2, g);
    // out = A @ g + b2
    spmm2_kernel<<<N_NODES / 4, 256, 0, stream>>>(row_ptr, edges, g, b2, out);
}

// Round 7
// 319.323 us; speedup vs baseline: 1.0950x; 1.0950x over previous
//
#include <hip/hip_runtime.h>
#include <hip/hip_bf16.h>

#define N_NODES 50000
#define N_EDGES 800000
#define IN_DIM 128
#define HIDDEN 128
#define OUT_DIM 40

#define SCAN_BS 1024
#define SCAN_BLOCKS ((N_NODES + SCAN_BS - 1) / SCAN_BS)   // 49
#define EDGE_BLOCKS (N_EDGES / 256)                       // 3125 exact

#define G1_ROWS 32
#define G1_BLOCKS ((N_NODES + G1_ROWS - 1) / G1_ROWS)     // 1563

struct __align__(8) Edge { int s; float w; };

// ---- 1) fused: hist (blocks [0,3125)) + gemm1 y=x@W1 (blocks [3125,4688)) --
// Independent work; heterogeneous blocks overlap atomic-latency hist with
// VALU-bound gemm1 so wall time ~ max, not sum.
__global__ __launch_bounds__(256) void hist_gemm1(const int* __restrict__ dst,
                                                  int* __restrict__ cnt,
                                                  const float* __restrict__ x,
                                                  const float* __restrict__ W1,
                                                  __hip_bfloat16* __restrict__ y)
{
    __shared__ float xs[G1_ROWS * IN_DIM];      // 16 KB
    int t = threadIdx.x;
    if (blockIdx.x < EDGE_BLOCKS) {
        int i = blockIdx.x * 256 + t;
        atomicAdd(&cnt[dst[i]], 1);
        return;
    }
    int bb = blockIdx.x - EDGE_BLOCKS;          // 0..1562
    int row0 = bb * G1_ROWS;
    // cooperative load of 32 rows (guarded)
    for (int idx = t; idx < G1_ROWS * IN_DIM; idx += 256) {
        int gr = row0 + (idx >> 7);
        xs[idx] = (gr < N_NODES) ? x[(long long)row0 * IN_DIM + idx] : 0.f;
    }
    __syncthreads();
    int col = t & 127;
    int rgrp = t >> 7;                           // 0 or 1 -> rows 0..15 / 16..31
    float acc[16];
    #pragma unroll
    for (int r = 0; r < 16; ++r) acc[r] = 0.f;
    #pragma unroll 4
    for (int k = 0; k < IN_DIM; ++k) {
        float wv = W1[k * HIDDEN + col];
        #pragma unroll
        for (int r = 0; r < 16; ++r)
            acc[r] = fmaf(xs[(rgrp * 16 + r) * IN_DIM + k], wv, acc[r]);
    }
    #pragma unroll
    for (int r = 0; r < 16; ++r) {
        int gr = row0 + rgrp * 16 + r;
        if (gr < N_NODES)
            y[(long long)gr * HIDDEN + col] = __float2bfloat16(acc[r]);
    }
}

// ---- 2a) per-block partial sums -------------------------------------------
__global__ __launch_bounds__(SCAN_BS) void scan_partial(const int* __restrict__ cnt,
                                                        int* __restrict__ block_sums)
{
    __shared__ int red[SCAN_BS / 64];
    int i = blockIdx.x * SCAN_BS + threadIdx.x;
    int v = (i < N_NODES) ? cnt[i] : 0;
    for (int off = 32; off > 0; off >>= 1) v += __shfl_down(v, off, 64);
    int wave = threadIdx.x >> 6, lane = threadIdx.x & 63;
    if (lane == 0) red[wave] = v;
    __syncthreads();
    if (threadIdx.x == 0) {
        int s = 0;
        #pragma unroll
        for (int wv = 0; wv < SCAN_BS / 64; ++wv) s += red[wv];
        block_sums[blockIdx.x] = s;
    }
}

// ---- 2b) scan the 49 block sums (one wave) --------------------------------
__global__ __launch_bounds__(64) void scan_sums(int* __restrict__ block_sums,
                                                int* __restrict__ row_ptr)
{
    int t = threadIdx.x;
    int v = (t < SCAN_BLOCKS) ? block_sums[t] : 0;
    int incl = v;
    for (int off = 1; off < 64; off <<= 1) {
        int u = __shfl_up(incl, off, 64);
        if (t >= off) incl += u;
    }
    if (t < SCAN_BLOCKS) block_sums[t] = incl - v;
    if (t == 0) row_ptr[N_NODES] = N_EDGES;
}

// ---- 2c) block-local exclusive scan + offset ------------------------------
__global__ __launch_bounds__(SCAN_BS) void scan_final(const int* __restrict__ cnt,
                                                      const int* __restrict__ block_sums,
                                                      int* __restrict__ row_ptr,
                                                      int* __restrict__ cursor)
{
    __shared__ int tmp[SCAN_BS];
    int t = threadIdx.x;
    int i = blockIdx.x * SCAN_BS + t;
    int v = (i < N_NODES) ? cnt[i] : 0;
    tmp[t] = v;
    __syncthreads();
    for (int off = 1; off < SCAN_BS; off <<= 1) {
        int u = (t >= off) ? tmp[t - off] : 0;
        __syncthreads();
        tmp[t] += u;
        __syncthreads();
    }
    if (i < N_NODES) {
        int excl = tmp[t] - v + block_sums[blockIdx.x];
        row_ptr[i] = excl;
        cursor[i]  = excl;
    }
}

// ---- 3) scatter edges into dst-sorted order (round-4 version) -------------
__global__ __launch_bounds__(256) void scatter_kernel(const int* __restrict__ src,
                                                      const int* __restrict__ dst,
                                                      const float* __restrict__ w,
                                                      int* __restrict__ cursor,
                                                      Edge* __restrict__ edges)
{
    int e = blockIdx.x * 256 + threadIdx.x;
    if (e >= N_EDGES) return;
    int d = dst[e];
    int pos = atomicAdd(&cursor[d], 1);
    Edge ed; ed.s = src[e]; ed.w = w[e];
    edges[pos] = ed;
}

// ---- spmm1 (feature-chunked): h1 = relu(A @ y + b1) -----------------------
// chunk = (blockIdx>>1)&3 -> each 32-col chunk (one 64B line per y-row,
// 3.2 MB working set) is gathered by one XCD pair -> L2-resident.
// 16 lanes per node (bf16x2 x16 = 32 cols), 16 nodes per 256-thread block.
__global__ __launch_bounds__(256) void spmm1_kernel(const int* __restrict__ row_ptr,
                                                    const Edge* __restrict__ edges,
                                                    const __hip_bfloat16* __restrict__ y,
                                                    const float* __restrict__ b1,
                                                    __hip_bfloat16* __restrict__ h1)
{
    int b = blockIdx.x;
    int chunk = (b >> 1) & 3;
    int node_group = (b >> 3) * 2 + (b & 1);       // 0..3125
    int t = threadIdx.x;
    int wv = t >> 6, lane = t & 63;
    int node = node_group * 16 + wv * 4 + (lane >> 4);
    if (node >= N_NODES) return;
    int sub = lane & 15;                            // col-pair within chunk
    int col2 = chunk * 16 + sub;                    // bf16x2 index, 0..63
    int beg = row_ptr[node];
    int end = row_ptr[node + 1];
    const __hip_bfloat162* yv = (const __hip_bfloat162*)y;
    float ax = 0.f, ay = 0.f;
    int j = beg;
    for (; j + 3 < end; j += 4) {
        Edge e0 = edges[j];
        Edge e1 = edges[j + 1];
        Edge e2 = edges[j + 2];
        Edge e3 = edges[j + 3];
        __hip_bfloat162 v0 = yv[(long long)e0.s * 64 + col2];
        __hip_bfloat162 v1 = yv[(long long)e1.s * 64 + col2];
        __hip_bfloat162 v2 = yv[(long long)e2.s * 64 + col2];
        __hip_bfloat162 v3 = yv[(long long)e3.s * 64 + col2];
        ax = fmaf(e0.w, __low2float(v0), ax);  ay = fmaf(e0.w, __high2float(v0), ay);
        ax = fmaf(e1.w, __low2float(v1), ax);  ay = fmaf(e1.w, __high2float(v1), ay);
        ax = fmaf(e2.w, __low2float(v2), ax);  ay = fmaf(e2.w, __high2float(v2), ay);
        ax = fmaf(e3.w, __low2float(v3), ax);  ay = fmaf(e3.w, __high2float(v3), ay);
    }
    for (; j < end; ++j) {
        Edge e0 = edges[j];
        __hip_bfloat162 v0 = yv[(long long)e0.s * 64 + col2];
        ax = fmaf(e0.w, __low2float(v0), ax);
        ay = fmaf(e0.w, __high2float(v0), ay);
    }
    float2 bv = ((const float2*)b1)[col2];
    __hip_bfloat162 hv;
    hv.x = __float2bfloat16(fmaxf(ax + bv.x, 0.f));
    hv.y = __float2bfloat16(fmaxf(ay + bv.y, 0.f));
    ((__hip_bfloat162*)h1)[(long long)node * 64 + col2] = hv;
}

// ---- gemm2: g = h1 @ W2 (bf16 in, bf16 out), 8 rows/block -----------------
#define G2_ROWS 8
__global__ __launch_bounds__(64) void gemm2_kernel(const __hip_bfloat16* __restrict__ h1,
                                                   const float* __restrict__ W2,
                                                   __hip_bfloat16* __restrict__ g)
{
    __shared__ float xs[G2_ROWS][HIDDEN];
    int row0 = blockIdx.x * G2_ROWS;
    int t = threadIdx.x;
    #pragma unroll
    for (int r = 0; r < G2_ROWS; ++r) {
        xs[r][t]      = __bfloat162float(h1[(long long)(row0 + r) * HIDDEN + t]);
        xs[r][t + 64] = __bfloat162float(h1[(long long)(row0 + r) * HIDDEN + t + 64]);
    }
    __syncthreads();
    if (t >= OUT_DIM) return;
    float acc[G2_ROWS];
    #pragma unroll
    for (int r = 0; r < G2_ROWS; ++r) acc[r] = 0.f;
    #pragma unroll 4
    for (int k = 0; k < HIDDEN; ++k) {
        float wv = W2[k * OUT_DIM + t];
        #pragma unroll
        for (int r = 0; r < G2_ROWS; ++r)
            acc[r] = fmaf(xs[r][k], wv, acc[r]);
    }
    #pragma unroll
    for (int r = 0; r < G2_ROWS; ++r)
        g[(long long)(row0 + r) * OUT_DIM + t] = __float2bfloat16(acc[r]);
}

// ---- spmm2: out = A @ g + b2; wave/node, 40 active lanes ------------------
__global__ __launch_bounds__(256) void spmm2_kernel(const int* __restrict__ row_ptr,
                                                    const Edge* __restrict__ edges,
                                                    const __hip_bfloat16* __restrict__ g,
                                                    const float* __restrict__ b2,
                                                    float* __restrict__ out)
{
    int node = blockIdx.x * 4 + (threadIdx.x >> 6);
    int lane = threadIdx.x & 63;
    if (node >= N_NODES) return;
    if (lane >= OUT_DIM) return;
    int beg = row_ptr[node];
    int end = row_ptr[node + 1];
    float acc = 0.f;
    int j = beg;
    for (; j + 3 < end; j += 4) {
        Edge e0 = edges[j];
        Edge e1 = edges[j + 1];
        Edge e2 = edges[j + 2];
        Edge e3 = edges[j + 3];
        float v0 = __bfloat162float(g[(long long)e0.s * OUT_DIM + lane]);
        float v1 = __bfloat162float(g[(long long)e1.s * OUT_DIM + lane]);
        float v2 = __bfloat162float(g[(long long)e2.s * OUT_DIM + lane]);
        float v3 = __bfloat162float(g[(long long)e3.s * OUT_DIM + lane]);
        acc = fmaf(e0.w, v0, acc);
        acc = fmaf(e1.w, v1, acc);
        acc = fmaf(e2.w, v2, acc);
        acc = fmaf(e3.w, v3, acc);
    }
    for (; j < end; ++j) {
        Edge e0 = edges[j];
        acc = fmaf(e0.w, __bfloat162float(g[(long long)e0.s * OUT_DIM + lane]), acc);
    }
    out[(long long)node * OUT_DIM + lane] = acc + b2[lane];
}

extern "C" void kernel_launch(void* const* d_in, const int* in_sizes, int n_in,
                              void* d_out, int out_size, void* d_ws, size_t ws_size,
                              hipStream_t stream)
{
    const float* x    = (const float*)d_in[0];
    const int*   esrc = (const int*)  d_in[1];
    const int*   edst = (const int*)  d_in[2];
    const float* ew   = (const float*)d_in[3];
    const float* W1   = (const float*)d_in[4];
    const float* b1   = (const float*)d_in[5];
    const float* W2   = (const float*)d_in[6];
    const float* b2   = (const float*)d_in[7];
    float* out = (float*)d_out;

    // workspace layout (~36.5 MB)
    __hip_bfloat16* y  = (__hip_bfloat16*)d_ws;                  // 12.8 MB
    __hip_bfloat16* h1 = y  + (size_t)N_NODES * HIDDEN;          // 12.8 MB
    __hip_bfloat16* g  = h1 + (size_t)N_NODES * HIDDEN;          // 4.0 MB
    int* row_ptr    = (int*)(g + (size_t)N_NODES * OUT_DIM);     // 50001 (pad 50176)
    int* cursor     = row_ptr + 50176;
    int* block_sums = cursor + 50176;                            // 64 ints
    Edge* edges     = (Edge*)(block_sums + 64);                  // 6.4 MB

    // CSR build + gemm1 (fused into the hist dispatch)
    hipMemsetAsync(cursor, 0, N_NODES * sizeof(int), stream);
    hist_gemm1<<<EDGE_BLOCKS + G1_BLOCKS, 256, 0, stream>>>(edst, cursor, x, W1, y);
    scan_partial<<<SCAN_BLOCKS, SCAN_BS, 0, stream>>>(cursor, block_sums);
    scan_sums<<<1, 64, 0, stream>>>(block_sums, row_ptr);
    scan_final<<<SCAN_BLOCKS, SCAN_BS, 0, stream>>>(cursor, block_sums, row_ptr, cursor);
    scatter_kernel<<<EDGE_BLOCKS, 256, 0, stream>>>(esrc, edst, ew, cursor, edges);

    // h1 = relu(A @ y + b1), feature-chunked for per-XCD L2 residency
    spmm1_kernel<<<3126 * 4, 256, 0, stream>>>(row_ptr, edges, y, b1, h1);
    // g = h1 @ W2
    gemm2_kernel<<<N_NODES / G2_ROWS, 64, 0, stream>>>(h1, W2, g);
    // out = A @ g + b2
    spmm2_kernel<<<(N_NODES + 3) / 4, 256, 0, stream>>>(row_ptr, edges, g, b2, out);
}

// Round 8
// 307.180 us; speedup vs baseline: 1.1383x; 1.0395x over previous
//
#include <hip/hip_runtime.h>
#include <hip/hip_bf16.h>

#define N_NODES 50000
#define N_EDGES 800000
#define IN_DIM 128
#define HIDDEN 128
#define OUT_DIM 40

#define SCAN_BS 1024
#define SCAN_BLOCKS ((N_NODES + SCAN_BS - 1) / SCAN_BS)   // 49
#define EDGE_BLOCKS (N_EDGES / 256)                       // 3125 exact

#define N_BUCKETS 8
#define BUCKET_NODES (N_NODES / N_BUCKETS)                // 6250
#define HIST_STRIDE 50176                                 // line-aligned copy stride
#define FIXCAP 110592                                     // staged records per bucket (33 sigma margin)

struct __align__(8) Edge { int s; float w; };

// ---- 1) buildA: ONE pass over edges. (a) histogram into XCD-private copy
// blockIdx&7 (own-L2 atomics, no cross-XCD bounce); (b) LDS-bin edges by
// dst-bucket and stage 16B records into fixed per-bucket regions with
// chunked (sequential) writes.
__global__ __launch_bounds__(256) void buildA(const int* __restrict__ src,
                                              const int* __restrict__ dst,
                                              const float* __restrict__ w,
                                              int* __restrict__ hist8,
                                              int* __restrict__ gfill,
                                              int4* __restrict__ staged)
{
    __shared__ int bin_cnt[N_BUCKETS];
    __shared__ int bin_base[N_BUCKETS];
    __shared__ int bin_fill[N_BUCKETS];
    int t = threadIdx.x;
    int i = blockIdx.x * 256 + t;                 // grid exact: 3125*256
    if (t < N_BUCKETS) { bin_cnt[t] = 0; bin_fill[t] = 0; }
    __syncthreads();
    int d = dst[i];
    int s = src[i];
    float wv = w[i];
    int copy = blockIdx.x & (N_BUCKETS - 1);
    atomicAdd(&hist8[copy * HIST_STRIDE + d], 1);
    unsigned q = (unsigned)d / BUCKET_NODES;
    atomicAdd(&bin_cnt[q], 1);
    __syncthreads();
    if (t < N_BUCKETS) bin_base[t] = atomicAdd(&gfill[t], bin_cnt[t]);
    __syncthreads();
    int off = atomicAdd(&bin_fill[q], 1);
    int pos = (int)q * FIXCAP + bin_base[q] + off;
    staged[pos] = make_int4(s, __float_as_int(wv), d, 0);
}

// ---- 2a) reduce 8 histogram copies -> cnt, plus per-block partial sums ----
__global__ __launch_bounds__(SCAN_BS) void scan_partial(const int* __restrict__ hist8,
                                                        int* __restrict__ cnt,
                                                        int* __restrict__ block_sums)
{
    __shared__ int red[SCAN_BS / 64];
    int i = blockIdx.x * SCAN_BS + threadIdx.x;
    int v = 0;
    if (i < N_NODES) {
        #pragma unroll
        for (int c = 0; c < N_BUCKETS; ++c) v += hist8[c * HIST_STRIDE + i];
        cnt[i] = v;
    }
    int s = v;
    for (int off = 32; off > 0; off >>= 1) s += __shfl_down(s, off, 64);
    int wave = threadIdx.x >> 6, lane = threadIdx.x & 63;
    if (lane == 0) red[wave] = s;
    __syncthreads();
    if (threadIdx.x == 0) {
        int tt = 0;
        #pragma unroll
        for (int wv = 0; wv < SCAN_BS / 64; ++wv) tt += red[wv];
        block_sums[blockIdx.x] = tt;
    }
}

// ---- 2b) scan the 49 block sums (one wave) --------------------------------
__global__ __launch_bounds__(64) void scan_sums(int* __restrict__ block_sums,
                                                int* __restrict__ row_ptr)
{
    int t = threadIdx.x;
    int v = (t < SCAN_BLOCKS) ? block_sums[t] : 0;
    int incl = v;
    for (int off = 1; off < 64; off <<= 1) {
        int u = __shfl_up(incl, off, 64);
        if (t >= off) incl += u;
    }
    if (t < SCAN_BLOCKS) block_sums[t] = incl - v;
    if (t == 0) row_ptr[N_NODES] = N_EDGES;
}

// ---- 2c) block-local exclusive scan + offset ------------------------------
__global__ __launch_bounds__(SCAN_BS) void scan_final(const int* __restrict__ cnt,
                                                      const int* __restrict__ block_sums,
                                                      int* __restrict__ row_ptr,
                                                      int* __restrict__ cursor)
{
    __shared__ int tmp[SCAN_BS];
    int t = threadIdx.x;
    int i = blockIdx.x * SCAN_BS + t;
    int v = (i < N_NODES) ? cnt[i] : 0;
    tmp[t] = v;
    __syncthreads();
    for (int off = 1; off < SCAN_BS; off <<= 1) {
        int u = (t >= off) ? tmp[t - off] : 0;
        __syncthreads();
        tmp[t] += u;
        __syncthreads();
    }
    if (i < N_NODES) {
        int excl = tmp[t] - v + block_sums[blockIdx.x];
        row_ptr[i] = excl;
        cursor[i]  = excl;
    }
}

// ---- 3) scatterB: per-bucket final scatter; bucket = blockIdx&7 so one XCD
// owns each bucket's 800KB edge slice + 25KB cursor slice -> L2 line merging.
__global__ __launch_bounds__(256) void scatterB(const int4* __restrict__ staged,
                                                const int* __restrict__ gfill,
                                                int* __restrict__ cursor,
                                                Edge* __restrict__ edges)
{
    int q   = blockIdx.x & (N_BUCKETS - 1);
    int idx = blockIdx.x >> 3;                 // 0..255 within bucket
    int n = gfill[q];
    long long base = (long long)q * FIXCAP;
    for (int i = idx * 256 + threadIdx.x; i < n; i += 256 * 256) {
        int4 st = staged[base + i];
        int pos = atomicAdd(&cursor[st.z], 1);
        Edge ed; ed.s = st.x; ed.w = __int_as_float(st.y);
        edges[pos] = ed;
    }
}

// ---- gemm1: y = x @ W1 (fp32 in, bf16 out), 16 rows/block -----------------
#define G1_ROWS 16
__global__ __launch_bounds__(128) void gemm1_kernel(const float* __restrict__ x,
                                                    const float* __restrict__ W1,
                                                    __hip_bfloat16* __restrict__ y)
{
    __shared__ float xs[G1_ROWS][IN_DIM];
    int row0 = blockIdx.x * G1_ROWS;
    int col = threadIdx.x;
    #pragma unroll
    for (int r = 0; r < G1_ROWS; ++r)
        xs[r][col] = x[(long long)(row0 + r) * IN_DIM + col];
    __syncthreads();
    float acc[G1_ROWS];
    #pragma unroll
    for (int r = 0; r < G1_ROWS; ++r) acc[r] = 0.f;
    #pragma unroll 4
    for (int k = 0; k < IN_DIM; ++k) {
        float wv = W1[k * HIDDEN + col];
        #pragma unroll
        for (int r = 0; r < G1_ROWS; ++r)
            acc[r] = fmaf(xs[r][k], wv, acc[r]);
    }
    #pragma unroll
    for (int r = 0; r < G1_ROWS; ++r)
        y[(long long)(row0 + r) * HIDDEN + col] = __float2bfloat16(acc[r]);
}

// ---- spmm1: h1 = relu(A @ y + b1); wave/node, bf16x2 per lane -------------
__global__ __launch_bounds__(256) void spmm1_kernel(const int* __restrict__ row_ptr,
                                                    const Edge* __restrict__ edges,
                                                    const __hip_bfloat16* __restrict__ y,
                                                    const float* __restrict__ b1,
                                                    __hip_bfloat16* __restrict__ h1)
{
    int node = blockIdx.x * 4 + (threadIdx.x >> 6);
    int lane = threadIdx.x & 63;
    if (node >= N_NODES) return;
    int beg = row_ptr[node];
    int end = row_ptr[node + 1];
    const __hip_bfloat162* yv = (const __hip_bfloat162*)y;
    float ax = 0.f, ay = 0.f;
    int j = beg;
    for (; j + 3 < end; j += 4) {
        Edge e0 = edges[j];
        Edge e1 = edges[j + 1];
        Edge e2 = edges[j + 2];
        Edge e3 = edges[j + 3];
        __hip_bfloat162 v0 = yv[(long long)e0.s * 64 + lane];
        __hip_bfloat162 v1 = yv[(long long)e1.s * 64 + lane];
        __hip_bfloat162 v2 = yv[(long long)e2.s * 64 + lane];
        __hip_bfloat162 v3 = yv[(long long)e3.s * 64 + lane];
        ax = fmaf(e0.w, __low2float(v0), ax);  ay = fmaf(e0.w, __high2float(v0), ay);
        ax = fmaf(e1.w, __low2float(v1), ax);  ay = fmaf(e1.w, __high2float(v1), ay);
        ax = fmaf(e2.w, __low2float(v2), ax);  ay = fmaf(e2.w, __high2float(v2), ay);
        ax = fmaf(e3.w, __low2float(v3), ax);  ay = fmaf(e3.w, __high2float(v3), ay);
    }
    for (; j < end; ++j) {
        Edge e0 = edges[j];
        __hip_bfloat162 v0 = yv[(long long)e0.s * 64 + lane];
        ax = fmaf(e0.w, __low2float(v0), ax);
        ay = fmaf(e0.w, __high2float(v0), ay);
    }
    float2 bv = ((const float2*)b1)[lane];
    __hip_bfloat162 hv;
    hv.x = __float2bfloat16(fmaxf(ax + bv.x, 0.f));
    hv.y = __float2bfloat16(fmaxf(ay + bv.y, 0.f));
    ((__hip_bfloat162*)h1)[(long long)node * 64 + lane] = hv;
}

// ---- gemm2: g = h1 @ W2 (bf16 in, bf16 out), 8 rows/block -----------------
#define G2_ROWS 8
__global__ __launch_bounds__(64) void gemm2_kernel(const __hip_bfloat16* __restrict__ h1,
                                                   const float* __restrict__ W2,
                                                   __hip_bfloat16* __restrict__ g)
{
    __shared__ float xs[G2_ROWS][HIDDEN];
    int row0 = blockIdx.x * G2_ROWS;
    int t = threadIdx.x;
    #pragma unroll
    for (int r = 0; r < G2_ROWS; ++r) {
        xs[r][t]      = __bfloat162float(h1[(long long)(row0 + r) * HIDDEN + t]);
        xs[r][t + 64] = __bfloat162float(h1[(long long)(row0 + r) * HIDDEN + t + 64]);
    }
    __syncthreads();
    if (t >= OUT_DIM) return;
    float acc[G2_ROWS];
    #pragma unroll
    for (int r = 0; r < G2_ROWS; ++r) acc[r] = 0.f;
    #pragma unroll 4
    for (int k = 0; k < HIDDEN; ++k) {
        float wv = W2[k * OUT_DIM + t];
        #pragma unroll
        for (int r = 0; r < G2_ROWS; ++r)
            acc[r] = fmaf(xs[r][k], wv, acc[r]);
    }
    #pragma unroll
    for (int r = 0; r < G2_ROWS; ++r)
        g[(long long)(row0 + r) * OUT_DIM + t] = __float2bfloat16(acc[r]);
}

// ---- spmm2: out = A @ g + b2; wave/node, 40 active lanes ------------------
__global__ __launch_bounds__(256) void spmm2_kernel(const int* __restrict__ row_ptr,
                                                    const Edge* __restrict__ edges,
                                                    const __hip_bfloat16* __restrict__ g,
                                                    const float* __restrict__ b2,
                                                    float* __restrict__ out)
{
    int node = blockIdx.x * 4 + (threadIdx.x >> 6);
    int lane = threadIdx.x & 63;
    if (node >= N_NODES) return;
    if (lane >= OUT_DIM) return;
    int beg = row_ptr[node];
    int end = row_ptr[node + 1];
    float acc = 0.f;
    int j = beg;
    for (; j + 3 < end; j += 4) {
        Edge e0 = edges[j];
        Edge e1 = edges[j + 1];
        Edge e2 = edges[j + 2];
        Edge e3 = edges[j + 3];
        float v0 = __bfloat162float(g[(long long)e0.s * OUT_DIM + lane]);
        float v1 = __bfloat162float(g[(long long)e1.s * OUT_DIM + lane]);
        float v2 = __bfloat162float(g[(long long)e2.s * OUT_DIM + lane]);
        float v3 = __bfloat162float(g[(long long)e3.s * OUT_DIM + lane]);
        acc = fmaf(e0.w, v0, acc);
        acc = fmaf(e1.w, v1, acc);
        acc = fmaf(e2.w, v2, acc);
        acc = fmaf(e3.w, v3, acc);
    }
    for (; j < end; ++j) {
        Edge e0 = edges[j];
        acc = fmaf(e0.w, __bfloat162float(g[(long long)e0.s * OUT_DIM + lane]), acc);
    }
    out[(long long)node * OUT_DIM + lane] = acc + b2[lane];
}

extern "C" void kernel_launch(void* const* d_in, const int* in_sizes, int n_in,
                              void* d_out, int out_size, void* d_ws, size_t ws_size,
                              hipStream_t stream)
{
    const float* x    = (const float*)d_in[0];
    const int*   esrc = (const int*)  d_in[1];
    const int*   edst = (const int*)  d_in[2];
    const float* ew   = (const float*)d_in[3];
    const float* W1   = (const float*)d_in[4];
    const float* b1   = (const float*)d_in[5];
    const float* W2   = (const float*)d_in[6];
    const float* b2   = (const float*)d_in[7];
    float* out = (float*)d_out;

    // workspace layout (~53 MB)
    __hip_bfloat16* y  = (__hip_bfloat16*)d_ws;                  // 12.8 MB
    __hip_bfloat16* h1 = y  + (size_t)N_NODES * HIDDEN;          // 12.8 MB
    __hip_bfloat16* g  = h1 + (size_t)N_NODES * HIDDEN;          // 4.0 MB
    int4* staged    = (int4*)(g + (size_t)N_NODES * OUT_DIM);    // 14.2 MB
    Edge* edges     = (Edge*)(staged + (size_t)N_BUCKETS * FIXCAP); // 6.4 MB
    int* hist8      = (int*)(edges + N_EDGES);                   // 1.6 MB
    int* gfill      = hist8 + N_BUCKETS * HIST_STRIDE;           // 16 ints (memset with hist8)
    int* cnt        = gfill + 16;                                // 200 KB
    int* row_ptr    = cnt + 50176;                               // 50001 (pad 50176)
    int* cursor     = row_ptr + 50176;
    int* block_sums = cursor + 50176;                            // 64 ints

    // CSR build: single-pass hist+stage, scan, bucket-owned final scatter
    hipMemsetAsync(hist8, 0, (N_BUCKETS * HIST_STRIDE + 16) * sizeof(int), stream);
    buildA<<<EDGE_BLOCKS, 256, 0, stream>>>(esrc, edst, ew, hist8, gfill, staged);
    scan_partial<<<SCAN_BLOCKS, SCAN_BS, 0, stream>>>(hist8, cnt, block_sums);
    scan_sums<<<1, 64, 0, stream>>>(block_sums, row_ptr);
    scan_final<<<SCAN_BLOCKS, SCAN_BS, 0, stream>>>(cnt, block_sums, row_ptr, cursor);
    scatterB<<<256 * N_BUCKETS, 256, 0, stream>>>(staged, gfill, cursor, edges);

    // y = x @ W1
    gemm1_kernel<<<N_NODES / G1_ROWS, 128, 0, stream>>>(x, W1, y);
    // h1 = relu(A @ y + b1)
    spmm1_kernel<<<(N_NODES + 3) / 4, 256, 0, stream>>>(row_ptr, edges, y, b1, h1);
    // g = h1 @ W2
    gemm2_kernel<<<N_NODES / G2_ROWS, 64, 0, stream>>>(h1, W2, g);
    // out = A @ g + b2
    spmm2_kernel<<<(N_NODES + 3) / 4, 256, 0, stream>>>(row_ptr, edges, g, b2, out);
}